// Round 21
// baseline (157.447 us; speedup 1.0000x reference)
//
#include <hip/hip_runtime.h>
#include <hip/hip_fp16.h>

#define IN_F   2048
#define OUT_F  2048
#define NNZ_   1048576
#define BATCH  8192
#define WMASK  (OUT_F * IN_F - 1)
#define TAIL_F ((size_t)6144 * OUT_F)     // d_out tail scratch (floats offset)

typedef __bf16 bf16x8 __attribute__((ext_vector_type(8)));
typedef float  f32x4  __attribute__((ext_vector_type(4)));
typedef unsigned int u32;

__device__ __forceinline__ float bfval(unsigned short b) {
    union { u32 u; float f; } t; t.u = ((u32)b) << 16; return t.f;
}
__device__ __forceinline__ unsigned short f2bf(float f) {
    union { float f; u32 u; } v; v.f = f;
    u32 u = v.u; u += 0x7FFF + ((u >> 16) & 1);   // RNE
    return (unsigned short)(u >> 16);
}
__device__ __forceinline__ float h2f(unsigned short b) {
    union { unsigned short u; __half h; } t; t.u = b; return __half2float(t.h);
}
__device__ __forceinline__ void gload_lds16(const void* g, void* l) {
    __builtin_amdgcn_global_load_lds(
        (const __attribute__((address_space(1))) unsigned int*)g,
        (__attribute__((address_space(3))) unsigned int*)l,
        16, 0, 0);
}

// ---- pass 1: per-block row histogram (blocks 0..255) + x->bf16 (rest) ----
__global__ void hist_xcvt_kernel(const int* __restrict__ coords,
                                 u32* __restrict__ gh,          // [2048][256]
                                 const float4* __restrict__ x,
                                 ushort4* __restrict__ xb) {
    if (blockIdx.x < 256) {
        __shared__ u32 lbin[2048];
        for (int i = threadIdx.x; i < 2048; i += 256) lbin[i] = 0u;
        __syncthreads();
        const int base = blockIdx.x * 4096;
#pragma unroll
        for (int j = 0; j < 16; ++j) {
            int c = coords[base + j * 256 + threadIdx.x] & WMASK;
            atomicAdd(&lbin[c >> 11], 1u);
        }
        __syncthreads();
        for (int r = threadIdx.x; r < 2048; r += 256)
            gh[r * 256 + blockIdx.x] = lbin[r];
    } else {
        const int t0     = (blockIdx.x - 256) * 256 + threadIdx.x;
        const int stride = 1536 * 256;
        for (int i = t0; i < BATCH * IN_F / 4; i += stride) {
            float4 v = x[i];
            ushort4 o;
            o.x = f2bf(v.x); o.y = f2bf(v.y); o.z = f2bf(v.z); o.w = f2bf(v.w);
            xb[i] = o;
        }
    }
}

// ---- pass 2a: exclusive cumsum over blocks per row; row totals ----
__global__ void scanA_kernel(u32* __restrict__ gh, u32* __restrict__ rt) {
    const int r = blockIdx.x * 256 + threadIdx.x;   // 8 blocks x 256 = 2048
    u32 run = 0;
    for (int b = 0; b < 256; ++b) {
        u32 t = gh[r * 256 + b];
        gh[r * 256 + b] = run;
        run += t;
    }
    rt[r] = run;
}

// ---- pass 2b: exclusive prefix over 2048 row totals -> rowbase[2049] ----
__global__ void scanB_kernel(const u32* __restrict__ rt, u32* __restrict__ rb) {
    __shared__ u32 s[2048];
    __shared__ u32 part[256];
    const int tid = threadIdx.x;
    for (int i = tid; i < 2048; i += 256) s[i] = rt[i];
    __syncthreads();
    u32 sum = 0;
#pragma unroll
    for (int j = 0; j < 8; ++j) sum += s[tid * 8 + j];
    part[tid] = sum;
    __syncthreads();
    if (tid == 0) {
        u32 run = 0;
        for (int i = 0; i < 256; ++i) { u32 t = part[i]; part[i] = run; run += t; }
    }
    __syncthreads();
    u32 run = part[tid];
#pragma unroll
    for (int j = 0; j < 8; ++j) { u32 t = s[tid * 8 + j]; s[tid * 8 + j] = run; run += t; }
    __syncthreads();
    for (int i = tid; i < 2048; i += 256) rb[i] = s[i];
    if (tid == 0) rb[2048] = NNZ_;
}

// ---- pass 3: slot each (col,w) into row-sorted arrays (no fabric atomics) ----
__global__ void place_kernel(const unsigned short* __restrict__ wbits,
                             const int* __restrict__ coords,
                             const u32* __restrict__ gh, const u32* __restrict__ rb,
                             unsigned short* __restrict__ cs, float* __restrict__ wsr) {
    __shared__ u32 cnt[2048];
    __shared__ u32 sbf, sfh;
    if (threadIdx.x == 0) { sbf = 0u; sfh = 0u; }
    __syncthreads();
    u32 mbf = 0u, mfh = 0u;
    for (int i = threadIdx.x; i < 512; i += 256) {
        unsigned short b = wbits[i];
        u32 abf = (((u32)b) << 16) & 0x7FFFFFFFu;
        u32 afh = (u32)(b & 0x7FFF);
        mbf = mbf > abf ? mbf : abf;
        mfh = mfh > afh ? mfh : afh;
    }
    atomicMax(&sbf, mbf); atomicMax(&sfh, mfh);
    __syncthreads();
    union { u32 u; float f; } tb; tb.u = sbf;
    float bmax = tb.f;
    float hmax = h2f((unsigned short)sfh);
    const int mode = (bmax > 1e-3f && bmax < 16.f) ? 0
                   : (hmax > 1e-3f && hmax < 16.f) ? 1 : 2;   // on HW: 2 (fp32)

    for (int r = threadIdx.x; r < 2048; r += 256)
        cnt[r] = rb[r] + gh[r * 256 + blockIdx.x];
    __syncthreads();

    const int base = blockIdx.x * 4096;
#pragma unroll
    for (int j = 0; j < 16; ++j) {
        int i = base + j * 256 + threadIdx.x;
        int c = coords[i] & WMASK;
        int row = c >> 11, col = c & 2047;
        float v;
        if (mode == 0)      v = bfval(wbits[i]);
        else if (mode == 1) v = h2f(wbits[i]);
        else                v = ((const float*)wbits)[i];
        u32 pos = atomicAdd(&cnt[row], 1u);   // LDS atomic (fast)
        cs[pos]  = (unsigned short)col;
        wsr[pos] = v;
    }
}

// ---- pass 4: per-row LDS fp32 accumulate + direct bf16 wb write ----
__global__ void accum_kernel(const u32* __restrict__ rb,
                             const unsigned short* __restrict__ cs,
                             const float* __restrict__ wsr,
                             ushort4* __restrict__ wb4) {
    __shared__ float lacc[8 * 2048];   // 64 KB
    const int tid = threadIdx.x;
    for (int i = tid; i < 16384; i += 256) lacc[i] = 0.f;
    __syncthreads();
#pragma unroll
    for (int j = 0; j < 8; ++j) {
        const int row = blockIdx.x * 8 + j;
        const u32 e = rb[row + 1];
        for (u32 i = rb[row] + tid; i < e; i += 256)
            atomicAdd(&lacc[j * 2048 + cs[i]], wsr[i]);   // LDS atomic
    }
    __syncthreads();
#pragma unroll
    for (int k = 0; k < 16; ++k) {
        const int e4 = k * 256 + tid;        // ushort4 index within block's 8 rows
        const int e  = e4 * 4;
        ushort4 o;
        o.x = f2bf(lacc[e]);     o.y = f2bf(lacc[e + 1]);
        o.z = f2bf(lacc[e + 2]); o.w = f2bf(lacc[e + 3]);
        wb4[(size_t)blockIdx.x * 4096 + e4] = o;
    }
}

// ---- 256x256 bf16 GEMM (r18 VERBATIM) ----
__global__ __launch_bounds__(1024, 4) void gemm256_kernel(
    const unsigned short* __restrict__ xb,
    const unsigned short* __restrict__ wb,
    float* __restrict__ out) {
    constexpr int K = IN_F;
    constexpr int NT = K / 64;

    __shared__ __align__(16) unsigned short As[2][256 * 64];
    __shared__ __align__(16) unsigned short Bs[2][256 * 64];

    const int tid  = threadIdx.x;
    const int lane = tid & 63;
    const int wave = tid >> 6;
    const int wr   = wave >> 2;
    const int wc   = wave & 3;
    const int frow = lane & 15;
    const int klan = lane >> 4;
    const int s0   = klan ^ (lane & 7);

    const int flat = blockIdx.x;
    const int swz  = (flat & 7) * 32 + (flat >> 3);
    const int tm   = swz & 31;
    const int tn   = swz >> 5;

    const unsigned short* srcA = xb + (size_t)tm * 256 * K;
    const unsigned short* srcB = wb + (size_t)tn * 256 * K;

    const int rloc  = lane >> 3;
    const int sslot = (lane & 7) ^ rloc;

    f32x4 acc[4][4] = {};

    auto stage = [&](int buf, int kt) {
        const size_t coff = (size_t)kt * 64 + sslot * 8;
#pragma unroll
        for (int c = 0; c < 2; ++c) {
            const int row = c * 128 + wave * 8;
            gload_lds16(srcA + (size_t)(row + rloc) * K + coff,
                        &As[buf][row * 64]);
        }
#pragma unroll
        for (int c = 0; c < 2; ++c) {
            const int row = c * 128 + wave * 8;
            gload_lds16(srcB + (size_t)(row + rloc) * K + coff,
                        &Bs[buf][row * 64]);
        }
    };

    auto compute = [&](int buf) {
#pragma unroll
        for (int ks = 0; ks < 2; ++ks) {
            const int sl = s0 ^ (ks * 4);
            bf16x8 af[4], bg[4];
#pragma unroll
            for (int mf = 0; mf < 4; ++mf)
                af[mf] = *(const bf16x8*)
                    &As[buf][(wr * 64 + mf * 16 + frow) * 64 + sl * 8];
#pragma unroll
            for (int nf = 0; nf < 4; ++nf)
                bg[nf] = *(const bf16x8*)
                    &Bs[buf][(wc * 64 + nf * 16 + frow) * 64 + sl * 8];
            __builtin_amdgcn_s_setprio(1);
#pragma unroll
            for (int mf = 0; mf < 4; ++mf)
#pragma unroll
                for (int nf = 0; nf < 4; ++nf)
                    acc[mf][nf] = __builtin_amdgcn_mfma_f32_16x16x32_bf16(
                        bg[nf], af[mf], acc[mf][nf], 0, 0, 0);   // swapped: D^T
            __builtin_amdgcn_s_setprio(0);
        }
    };

    stage(0, 0);
    stage(1, 1);

    for (int kt = 0; kt < NT - 2; ++kt) {
        asm volatile("s_waitcnt vmcnt(4)" ::: "memory");
        __builtin_amdgcn_s_barrier();
        compute(kt & 1);
        asm volatile("" ::: "memory");
        __builtin_amdgcn_s_barrier();
        stage(kt & 1, kt + 2);
    }
    asm volatile("s_waitcnt vmcnt(4)" ::: "memory");
    __builtin_amdgcn_s_barrier();
    compute((NT - 2) & 1);
    asm volatile("" ::: "memory");
    __builtin_amdgcn_s_barrier();
    asm volatile("s_waitcnt vmcnt(0)" ::: "memory");
    __builtin_amdgcn_s_barrier();
    compute((NT - 1) & 1);

    const int orow0 = tm * 256 + wr * 64 + frow;
    const int ocol0 = tn * 256 + wc * 64 + klan * 4;
#pragma unroll
    for (int mf = 0; mf < 4; ++mf)
#pragma unroll
        for (int nf = 0; nf < 4; ++nf) {
            float4 v;
            v.x = acc[mf][nf][0]; v.y = acc[mf][nf][1];
            v.z = acc[mf][nf][2]; v.w = acc[mf][nf][3];
            *(float4*)&out[(size_t)(orow0 + mf * 16) * OUT_F
                           + ocol0 + nf * 16] = v;
        }
}

extern "C" void kernel_launch(void* const* d_in, const int* in_sizes, int n_in,
                              void* d_out, int out_size, void* d_ws, size_t ws_size,
                              hipStream_t stream) {
    const float*          x      = (const float*)d_in[0];
    const unsigned short* wbits  = (const unsigned short*)d_in[1];  // fp32-delivered
    const int*            coords = (const int*)d_in[2];             // int32
    float*                out    = (float*)d_out;                   // fp32

    const size_t MB = 1024 * 1024;
    // ws: wb bf16 (8 MiB) | xb bf16 (32 MiB)     [ws >= 40 MiB proven r10+]
    unsigned short* wb = (unsigned short*)d_ws;
    unsigned short* xb = (unsigned short*)((char*)d_ws + 8 * MB);
    // d_out tail scratch (dead until GEMM overwrites, consumed before):
    //   gh [2048][256] u32 (2 MB) | rt u32[2048] | rb u32[2049] |
    //   cs u16[1M] (2 MB) | wsr f32[1M] (4 MB)
    u32*            gh  = (u32*)(out + TAIL_F);
    u32*            rt  = gh + 2048 * 256;
    u32*            rb  = rt + 2048;
    unsigned short* cs  = (unsigned short*)((char*)(out + TAIL_F) + 4 * MB);
    float*          wsr = (float*)((char*)(out + TAIL_F) + 8 * MB);
    (void)ws_size; (void)in_sizes; (void)n_in; (void)out_size;

    hist_xcvt_kernel<<<1792, 256, 0, stream>>>(coords, gh, (const float4*)x,
                                               (ushort4*)xb);
    scanA_kernel<<<8, 256, 0, stream>>>(gh, rt);
    scanB_kernel<<<1, 256, 0, stream>>>(rt, rb);
    place_kernel<<<256, 256, 0, stream>>>(wbits, coords, gh, rb, cs, wsr);
    accum_kernel<<<256, 256, 0, stream>>>(rb, cs, wsr, (ushort4*)wb);

    gemm256_kernel<<<256, 1024, 0, stream>>>(xb, wb, out);
}